// Round 1
// baseline (715.061 us; speedup 1.0000x reference)
//
#include <hip/hip_runtime.h>

#define NG   16       // groups
#define CG   16       // channels per group
#define NB   64       // batch
#define CC   256      // channels
#define HW   3136     // 56*56
#define HW4  784      // HW/4
#define MTOT (NB*HW)  // 200704 samples per channel
#define Q4   (NB*HW4) // 50176 float4-quads per channel
#define EPSV 1e-3f
#define NTRI 136      // 16*17/2 upper-triangular entries

// ws layout (floats):
//   [0,256)        chsum   per-channel sums (atomic accumulated)
//   [256,2432)     cross   per-group triangular second moments (16*136)
//   [2432,6528)    wmw     per-group scaled whitening matrix (16*256)
//   [6528,6784)    ob      per-channel fused offset
#define WS_CROSS 256
#define WS_WMW   2432
#define WS_OB    6528

// ---------------- Pass 1: per-group covariance stats ----------------
__global__ __launch_bounds__(256, 2) void stats_kernel(const float* __restrict__ X,
                                                       float* __restrict__ ws) {
    const int g   = blockIdx.y;
    const int tid = threadIdx.x;
    const float4* X4 = (const float4*)X;

    float cross[NTRI];
    float csum[CG];
#pragma unroll
    for (int i = 0; i < NTRI; ++i) cross[i] = 0.f;
#pragma unroll
    for (int c = 0; c < CG; ++c) csum[c] = 0.f;

    // 49 blocks * 256 threads = 12544 threads/group; 4 quads each = 50176
#pragma unroll 1
    for (int it = 0; it < 4; ++it) {
        int q4 = it * 12544 + blockIdx.x * 256 + tid;
        int n  = q4 / HW4;
        int p4 = q4 - n * HW4;
        int base = n * (CC * HW4) + (g * CG) * HW4 + p4;

        float4 v[CG];
#pragma unroll
        for (int c = 0; c < CG; ++c) v[c] = X4[base + c * HW4];

#pragma unroll
        for (int c = 0; c < CG; ++c)
            csum[c] += (v[c].x + v[c].y) + (v[c].z + v[c].w);

        int i = 0;
#pragma unroll
        for (int c = 0; c < CG; ++c) {
#pragma unroll
            for (int d = c; d < CG; ++d) {
                cross[i] += v[c].x * v[d].x + v[c].y * v[d].y +
                            v[c].z * v[d].z + v[c].w * v[d].w;
                ++i;
            }
        }
    }

    // wave-level butterfly reduction, then lane 0 atomics
    const int lane = tid & 63;
#pragma unroll
    for (int c = 0; c < CG; ++c) {
        float v = csum[c];
        v += __shfl_xor(v, 32); v += __shfl_xor(v, 16); v += __shfl_xor(v, 8);
        v += __shfl_xor(v, 4);  v += __shfl_xor(v, 2);  v += __shfl_xor(v, 1);
        csum[c] = v;
    }
#pragma unroll
    for (int i = 0; i < NTRI; ++i) {
        float v = cross[i];
        v += __shfl_xor(v, 32); v += __shfl_xor(v, 16); v += __shfl_xor(v, 8);
        v += __shfl_xor(v, 4);  v += __shfl_xor(v, 2);  v += __shfl_xor(v, 1);
        cross[i] = v;
    }
    if (lane == 0) {
#pragma unroll
        for (int c = 0; c < CG; ++c)
            atomicAdd(&ws[g * CG + c], csum[c]);
#pragma unroll
        for (int i = 0; i < NTRI; ++i)
            atomicAdd(&ws[WS_CROSS + g * NTRI + i], cross[i]);
    }
}

// ---------------- Pass 2: sigma -> sigma^(-1/2) via Newton-Schulz ----------------
__global__ __launch_bounds__(256) void newton_kernel(const float* __restrict__ weight,
                                                     const float* __restrict__ bias,
                                                     float* __restrict__ ws) {
    __shared__ float Y[CG][CG + 1], Z[CG][CG + 1], T[CG][CG + 1];
    __shared__ float mean_s[CG];
    __shared__ float red[256];
    __shared__ float s_norm;

    const int g   = blockIdx.x;
    const int tid = threadIdx.x;
    const int c   = tid >> 4;
    const int d   = tid & 15;

    if (tid < CG) mean_s[tid] = ws[g * CG + tid] * (1.0f / MTOT);
    __syncthreads();

    const int cc = min(c, d), dd = max(c, d);
    const int idx = cc * CG + dd - (cc * (cc + 1)) / 2;
    float sig = ws[WS_CROSS + g * NTRI + idx] * (1.0f / MTOT)
              - mean_s[c] * mean_s[d] + ((c == d) ? EPSV : 0.f);

    // Frobenius norm
    red[tid] = sig * sig;
    __syncthreads();
    for (int s = 128; s > 0; s >>= 1) {
        if (tid < s) red[tid] += red[tid + s];
        __syncthreads();
    }
    if (tid == 0) s_norm = sqrtf(red[0]);
    __syncthreads();
    const float s = s_norm;

    Y[c][d] = sig / s;
    Z[c][d] = (c == d) ? 1.f : 0.f;
    __syncthreads();

    for (int itn = 0; itn < 12; ++itn) {
        float t = 0.f;
#pragma unroll
        for (int k = 0; k < CG; ++k) t += Z[c][k] * Y[k][d];
        t = ((c == d) ? 3.f : 0.f) - t;
        __syncthreads();
        T[c][d] = t;
        __syncthreads();
        float yn = 0.f, zn = 0.f;
#pragma unroll
        for (int k = 0; k < CG; ++k) {
            yn += Y[c][k] * T[k][d];
            zn += T[c][k] * Z[k][d];
        }
        __syncthreads();
        Y[c][d] = 0.5f * yn;
        Z[c][d] = 0.5f * zn;
        __syncthreads();
    }

    // wm = Z / sqrt(s); fold in weight, bias, mean
    const float wm  = Z[c][d] / sqrtf(s);
    const float w   = weight[g * CG + c];
    const float wmw = wm * w;
    ws[WS_WMW + g * 256 + c * CG + d] = wmw;

    T[c][d] = wmw * mean_s[d];
    __syncthreads();
    if (d == 0) {
        float acc = 0.f;
#pragma unroll
        for (int k = 0; k < CG; ++k) acc += T[c][k];
        ws[WS_OB + g * CG + c] = bias[g * CG + c] - acc;
    }
}

// ---------------- Pass 3: apply whitening ----------------
__global__ __launch_bounds__(256, 4) void apply_kernel(const float* __restrict__ X,
                                                       const float* __restrict__ ws,
                                                       float* __restrict__ out) {
    __shared__ float wmw_s[CG][CG];
    __shared__ float ob_s[CG];

    const int g   = blockIdx.y;
    const int tid = threadIdx.x;

    wmw_s[tid >> 4][tid & 15] = ws[WS_WMW + g * 256 + tid];
    if (tid < CG) ob_s[tid] = ws[WS_OB + g * CG + tid];
    __syncthreads();

    const int q4 = blockIdx.x * 256 + tid;     // grid.x = 196 -> exactly Q4
    const int n  = q4 / HW4;
    const int p4 = q4 - n * HW4;
    const int base = n * (CC * HW4) + (g * CG) * HW4 + p4;

    const float4* X4 = (const float4*)X;
    float4* O4 = (float4*)out;

    float4 v[CG];
#pragma unroll
    for (int cdx = 0; cdx < CG; ++cdx) v[cdx] = X4[base + cdx * HW4];

#pragma unroll
    for (int c = 0; c < CG; ++c) {
        const float o = ob_s[c];
        float4 acc;
        acc.x = o; acc.y = o; acc.z = o; acc.w = o;
#pragma unroll
        for (int d = 0; d < CG; ++d) {
            const float w = wmw_s[c][d];
            acc.x += w * v[d].x; acc.y += w * v[d].y;
            acc.z += w * v[d].z; acc.w += w * v[d].w;
        }
        O4[base + c * HW4] = acc;
    }
}

extern "C" void kernel_launch(void* const* d_in, const int* in_sizes, int n_in,
                              void* d_out, int out_size, void* d_ws, size_t ws_size,
                              hipStream_t stream) {
    const float* X      = (const float*)d_in[0];
    const float* weight = (const float*)d_in[1];
    const float* bias   = (const float*)d_in[2];
    float* out = (float*)d_out;
    float* ws  = (float*)d_ws;

    // zero the accumulator region (ws is poisoned 0xAA before every call)
    hipMemsetAsync(ws, 0, WS_WMW * sizeof(float), stream);

    dim3 g1(49, NG);
    stats_kernel<<<g1, 256, 0, stream>>>(X, ws);

    newton_kernel<<<NG, 256, 0, stream>>>(weight, bias, ws);

    dim3 g3(196, NG);
    apply_kernel<<<g3, 256, 0, stream>>>(X, ws, out);
}

// Round 2
// 419.763 us; speedup vs baseline: 1.7035x; 1.7035x over previous
//
#include <hip/hip_runtime.h>

#define NG   16       // groups
#define CG   16       // channels per group
#define NB   64       // batch
#define CC   256      // channels
#define HW   3136     // 56*56
#define HW4  784      // HW/4
#define MTOT (NB*HW)  // 200704 samples per channel
#define Q4   (NB*HW4) // 50176 float4-quads per channel
#define EPSV 1e-3f
#define NTRI 136      // 16*17/2 upper-triangular entries
#define NRED (CG+NTRI) // 152 reduced values per group

// ws layout (floats):
//   [0,256)        chsum   per-channel sums (atomic accumulated)
//   [256,2432)     cross   per-group triangular second moments (16*136)
//   [2432,6528)    wmw     per-group scaled whitening matrix (16*256)
//   [6528,6784)    ob      per-channel fused offset
#define WS_CROSS 256
#define WS_WMW   2432
#define WS_OB    6528

// ---------------- Pass 1: per-group covariance stats ----------------
// launch_bounds(256,1): allow up to 512 VGPRs so the 136 triangular
// accumulators + 16 float4 channel values (~230 regs) stay in registers.
// R0 post-mortem: (256,2) capped at 128 VGPRs -> 285 MB of spill traffic.
__global__ __launch_bounds__(256, 1) void stats_kernel(const float* __restrict__ X,
                                                       float* __restrict__ ws) {
    const int g   = blockIdx.y;
    const int tid = threadIdx.x;
    const float4* X4 = (const float4*)X;

    float cross[NTRI];
    float csum[CG];
#pragma unroll
    for (int i = 0; i < NTRI; ++i) cross[i] = 0.f;
#pragma unroll
    for (int c = 0; c < CG; ++c) csum[c] = 0.f;

    // 28 blocks * 256 threads = 7168 threads/group; 7 quads each = 50176 = Q4
#pragma unroll 1
    for (int it = 0; it < 7; ++it) {
        int q4 = it * 7168 + blockIdx.x * 256 + tid;
        int n  = q4 / HW4;
        int p4 = q4 - n * HW4;
        int base = n * (CC * HW4) + (g * CG) * HW4 + p4;

        float4 v[CG];
#pragma unroll
        for (int c = 0; c < CG; ++c) v[c] = X4[base + c * HW4];

#pragma unroll
        for (int c = 0; c < CG; ++c)
            csum[c] += (v[c].x + v[c].y) + (v[c].z + v[c].w);

        int i = 0;
#pragma unroll
        for (int c = 0; c < CG; ++c) {
#pragma unroll
            for (int d = c; d < CG; ++d) {
                cross[i] += v[c].x * v[d].x + v[c].y * v[d].y +
                            v[c].z * v[d].z + v[c].w * v[d].w;
                ++i;
            }
        }
    }

    // wave-level butterfly reduction
    const int lane = tid & 63;
    const int w    = tid >> 6;
#pragma unroll
    for (int c = 0; c < CG; ++c) {
        float v = csum[c];
        v += __shfl_xor(v, 32); v += __shfl_xor(v, 16); v += __shfl_xor(v, 8);
        v += __shfl_xor(v, 4);  v += __shfl_xor(v, 2);  v += __shfl_xor(v, 1);
        csum[c] = v;
    }
#pragma unroll
    for (int i = 0; i < NTRI; ++i) {
        float v = cross[i];
        v += __shfl_xor(v, 32); v += __shfl_xor(v, 16); v += __shfl_xor(v, 8);
        v += __shfl_xor(v, 4);  v += __shfl_xor(v, 2);  v += __shfl_xor(v, 1);
        cross[i] = v;
    }

    // block-level combine in LDS, then one atomicAdd per value per block
    __shared__ float part[4][NRED];
    if (lane == 0) {
#pragma unroll
        for (int c = 0; c < CG; ++c) part[w][c] = csum[c];
#pragma unroll
        for (int i = 0; i < NTRI; ++i) part[w][CG + i] = cross[i];
    }
    __syncthreads();
    if (tid < NRED) {
        float s = part[0][tid] + part[1][tid] + part[2][tid] + part[3][tid];
        if (tid < CG) atomicAdd(&ws[g * CG + tid], s);
        else          atomicAdd(&ws[WS_CROSS + g * NTRI + (tid - CG)], s);
    }
}

// ---------------- Pass 2: sigma -> sigma^(-1/2) via Newton-Schulz ----------------
__global__ __launch_bounds__(256) void newton_kernel(const float* __restrict__ weight,
                                                     const float* __restrict__ bias,
                                                     float* __restrict__ ws) {
    __shared__ float Y[CG][CG + 1], Z[CG][CG + 1], T[CG][CG + 1];
    __shared__ float mean_s[CG];
    __shared__ float red[256];
    __shared__ float s_norm;

    const int g   = blockIdx.x;
    const int tid = threadIdx.x;
    const int c   = tid >> 4;
    const int d   = tid & 15;

    if (tid < CG) mean_s[tid] = ws[g * CG + tid] * (1.0f / MTOT);
    __syncthreads();

    const int cc = min(c, d), dd = max(c, d);
    const int idx = cc * CG + dd - (cc * (cc + 1)) / 2;
    float sig = ws[WS_CROSS + g * NTRI + idx] * (1.0f / MTOT)
              - mean_s[c] * mean_s[d] + ((c == d) ? EPSV : 0.f);

    // Frobenius norm
    red[tid] = sig * sig;
    __syncthreads();
    for (int s = 128; s > 0; s >>= 1) {
        if (tid < s) red[tid] += red[tid + s];
        __syncthreads();
    }
    if (tid == 0) s_norm = sqrtf(red[0]);
    __syncthreads();
    const float s = s_norm;

    Y[c][d] = sig / s;
    Z[c][d] = (c == d) ? 1.f : 0.f;
    __syncthreads();

    for (int itn = 0; itn < 12; ++itn) {
        float t = 0.f;
#pragma unroll
        for (int k = 0; k < CG; ++k) t += Z[c][k] * Y[k][d];
        t = ((c == d) ? 3.f : 0.f) - t;
        __syncthreads();
        T[c][d] = t;
        __syncthreads();
        float yn = 0.f, zn = 0.f;
#pragma unroll
        for (int k = 0; k < CG; ++k) {
            yn += Y[c][k] * T[k][d];
            zn += T[c][k] * Z[k][d];
        }
        __syncthreads();
        Y[c][d] = 0.5f * yn;
        Z[c][d] = 0.5f * zn;
        __syncthreads();
    }

    // wm = Z / sqrt(s); fold in weight, bias, mean
    const float wm  = Z[c][d] / sqrtf(s);
    const float w   = weight[g * CG + c];
    const float wmw = wm * w;
    ws[WS_WMW + g * 256 + c * CG + d] = wmw;

    T[c][d] = wmw * mean_s[d];
    __syncthreads();
    if (d == 0) {
        float acc = 0.f;
#pragma unroll
        for (int k = 0; k < CG; ++k) acc += T[c][k];
        ws[WS_OB + g * CG + c] = bias[g * CG + c] - acc;
    }
}

// ---------------- Pass 3: apply whitening ----------------
__global__ __launch_bounds__(256, 4) void apply_kernel(const float* __restrict__ X,
                                                       const float* __restrict__ ws,
                                                       float* __restrict__ out) {
    __shared__ float wmw_s[CG][CG];
    __shared__ float ob_s[CG];

    const int g   = blockIdx.y;
    const int tid = threadIdx.x;

    wmw_s[tid >> 4][tid & 15] = ws[WS_WMW + g * 256 + tid];
    if (tid < CG) ob_s[tid] = ws[WS_OB + g * CG + tid];
    __syncthreads();

    const int q4 = blockIdx.x * 256 + tid;     // grid.x = 196 -> exactly Q4
    const int n  = q4 / HW4;
    const int p4 = q4 - n * HW4;
    const int base = n * (CC * HW4) + (g * CG) * HW4 + p4;

    const float4* X4 = (const float4*)X;
    float4* O4 = (float4*)out;

    float4 v[CG];
#pragma unroll
    for (int cdx = 0; cdx < CG; ++cdx) v[cdx] = X4[base + cdx * HW4];

#pragma unroll
    for (int c = 0; c < CG; ++c) {
        const float o = ob_s[c];
        float4 acc;
        acc.x = o; acc.y = o; acc.z = o; acc.w = o;
#pragma unroll
        for (int d = 0; d < CG; ++d) {
            const float w = wmw_s[c][d];
            acc.x += w * v[d].x; acc.y += w * v[d].y;
            acc.z += w * v[d].z; acc.w += w * v[d].w;
        }
        O4[base + c * HW4] = acc;
    }
}

extern "C" void kernel_launch(void* const* d_in, const int* in_sizes, int n_in,
                              void* d_out, int out_size, void* d_ws, size_t ws_size,
                              hipStream_t stream) {
    const float* X      = (const float*)d_in[0];
    const float* weight = (const float*)d_in[1];
    const float* bias   = (const float*)d_in[2];
    float* out = (float*)d_out;
    float* ws  = (float*)d_ws;

    // zero the accumulator region (ws is poisoned 0xAA before every call)
    hipMemsetAsync(ws, 0, WS_WMW * sizeof(float), stream);

    dim3 g1(28, NG);
    stats_kernel<<<g1, 256, 0, stream>>>(X, ws);

    newton_kernel<<<NG, 256, 0, stream>>>(weight, bias, ws);

    dim3 g3(196, NG);
    apply_kernel<<<g3, 256, 0, stream>>>(X, ws, out);
}